// Round 17
// baseline (889.740 us; speedup 1.0000x reference)
//
#include <hip/hip_runtime.h>
#include <hip/hip_bf16.h>
#include <math.h>

namespace {

constexpr int Bb = 16;
constexpr int Ss = 1024;
constexpr int Dd = 1024;
constexpr int Hh = 16;
constexpr int HD = 64;
constexpr int MLPH = 2730;
constexpr int MLPH_PAD = 2752;
constexpr int ADA_LD = 6144;
constexpr int NR = Bb * Ss; // 16384 rows

typedef __attribute__((ext_vector_type(8))) short bf16x8;
typedef __attribute__((ext_vector_type(4))) float f32x4;
typedef __hip_bfloat16 bf16;
typedef unsigned int u32;

__device__ __forceinline__ float bf2f(bf16 v){ return __bfloat162float(v); }
__device__ __forceinline__ bf16 f2bf(float v){ return __float2bfloat16(v); }
__device__ __forceinline__ short f2bfs(float v){ bf16 t = __float2bfloat16(v); return __builtin_bit_cast(short, t); }

__device__ __forceinline__ f32x4 mfma16(bf16x8 a, bf16x8 b, f32x4 c){
  return __builtin_amdgcn_mfma_f32_16x16x32_bf16(a, b, c, 0, 0, 0);
}

// async global->LDS, 16B per lane; LDS dest linear (wave base + lane*16)
__device__ __forceinline__ void gload16(const void* g, void* l){
  __builtin_amdgcn_global_load_lds(
      (const __attribute__((address_space(1))) u32*)g,
      (__attribute__((address_space(3))) u32*)l, 16, 0, 0);
}

// opaque LDS b128 read (ordering carried by explicit waitcnt fences)
__device__ __forceinline__ bf16x8 dsr128(const short* p){
  f32x4 r;
  asm volatile("ds_read_b128 %0, %1" : "=v"(r) : "v"((u32)(size_t)p));
  return __builtin_bit_cast(bf16x8, r);
}

// ---------------- small kernels ----------------

__global__ void k_silu(const float* __restrict__ c, float* __restrict__ out, int n){
  int i = blockIdx.x*256 + threadIdx.x;
  if(i < n){ float v = c[i]; out[i] = v / (1.f + __expf(-v)); }
}

__global__ __launch_bounds__(256) void k_ada(const float* __restrict__ sc,
    const float* __restrict__ w, const float* __restrict__ bias, float* __restrict__ ada){
  __shared__ float red[4][Bb][64];
  int tid = threadIdx.x;
  int jj = tid & 63, ks = tid >> 6;
  int j = blockIdx.x*64 + jj;
  float acc[Bb];
  #pragma unroll
  for(int b=0;b<Bb;++b) acc[b] = 0.f;
  for(int k=ks*256; k<ks*256+256; ++k){
    float wv = w[(size_t)k*ADA_LD + j];
    #pragma unroll
    for(int b=0;b<Bb;++b) acc[b] += sc[b*Dd + k] * wv;
  }
  #pragma unroll
  for(int b=0;b<Bb;++b) red[ks][b][jj] = acc[b];
  __syncthreads();
  #pragma unroll
  for(int rep=0;rep<4;++rep){
    int idx = rep*256 + tid;
    int b = idx >> 6, j2 = idx & 63;
    float s = red[0][b][j2]+red[1][b][j2]+red[2][b][j2]+red[3][b][j2];
    ada[(size_t)b*ADA_LD + blockIdx.x*64 + j2] = s + bias[blockIdx.x*64 + j2];
  }
}

__global__ void k_rope_tab(float2* __restrict__ tab){
  int i = blockIdx.x*256 + threadIdx.x;
  int s = i >> 5, f = i & 31;
  float inv = powf(10000.f, -((float)(2*f)) / 64.f);
  float fr = (float)s * inv;
  float sv, cv;
  sincosf(fr, &sv, &cv);
  tab[i] = make_float2(cv, sv);
}

// in f32 [R,C] -> out bf16 [C,Rpad], zero-filled for col in [R,Rpad)
__global__ void k_transpose(const float* __restrict__ in, bf16* __restrict__ out,
                            int R, int C, int Rpad){
  __shared__ short tile[32][33];
  int tx = threadIdx.x & 31, ty = threadIdx.x >> 5;
  int tr0 = blockIdx.x*32, tc0 = blockIdx.y*32;
  #pragma unroll
  for(int i=0;i<4;++i){
    int r = tr0 + ty + i*8, cc = tc0 + tx;
    short v = 0;
    if(r < R && cc < C) v = f2bfs(in[(size_t)r*C + cc]);
    tile[ty+i*8][tx] = v;
  }
  __syncthreads();
  #pragma unroll
  for(int i=0;i<4;++i){
    int oc = tc0 + ty + i*8;
    int orow = tr0 + tx;
    if(oc < C && orow < Rpad)
      out[(size_t)oc*Rpad + orow] = __builtin_bit_cast(bf16, tile[tx][ty+i*8]);
  }
}

// RMSNorm over D + adaLN modulate
__global__ __launch_bounds__(256) void k_norm_mod(const float* __restrict__ x,
    const float* __restrict__ w, const float* __restrict__ shift, const float* __restrict__ scale,
    bf16* __restrict__ out){
  int r = blockIdx.x;
  int b = r >> 10;
  int t = threadIdx.x;
  const float* xr = x + (size_t)r*Dd;
  float v[4]; float ss = 0.f;
  #pragma unroll
  for(int i=0;i<4;++i){
    float f = xr[t*4+i];
    v[i] = f; ss += f*f;
  }
  #pragma unroll
  for(int m=1;m<64;m<<=1) ss += __shfl_xor(ss, m);
  __shared__ float red[4];
  if((t & 63) == 0) red[t>>6] = ss;
  __syncthreads();
  float tot = red[0]+red[1]+red[2]+red[3];
  float rms = rsqrtf(tot * (1.f/Dd) + 1e-6f);
  #pragma unroll
  for(int i=0;i<4;++i){
    int ccol = t*4+i;
    float h = v[i]*rms*w[ccol];
    float scv = scale[(size_t)b*ADA_LD + ccol];
    float shv = shift[(size_t)b*ADA_LD + ccol];
    out[(size_t)r*Dd + ccol] = f2bf(h*(1.f+scv) + shv);
  }
}

// per-(b,s) RMSNorm(64)+RoPE for q,k of qkv, in place, vectorized.
// Q additionally scaled by 0.125*log2(e) (score scale folded; attn uses exp2).
__global__ __launch_bounds__(256) void k_qknorm(bf16* __restrict__ qkv,
    const float* __restrict__ qw, const float* __restrict__ kw,
    const float2* __restrict__ tab){
  int bs = blockIdx.x;
  int s = bs & (Ss-1);
  int tid = threadIdx.x;
  int wv = tid >> 6, lane = tid & 63;
  int isK = wv >> 1;
  int chunk = (wv & 1)*64 + lane;
  int c = chunk & 7;
  int h = chunk >> 3;
  int dih = c*8;
  bf16* p = qkv + (size_t)bs*3072 + isK*Dd + h*HD + dih;
  bf16x8 v = *(const bf16x8*)p;
  float x[8]; float ss = 0.f;
  #pragma unroll
  for(int i=0;i<8;++i){ x[i] = bf2f(__builtin_bit_cast(bf16,(short)v[i])); ss += x[i]*x[i]; }
  ss += __shfl_xor(ss,1); ss += __shfl_xor(ss,2); ss += __shfl_xor(ss,4);
  float rms = rsqrtf(ss*(1.f/HD) + 1e-6f);
  const float* wn = isK ? kw : qw;
  float xn[8];
  #pragma unroll
  for(int i=0;i<8;++i) xn[i] = x[i]*rms*wn[dih+i];
  u32 pk[4], pq[4];
  #pragma unroll
  for(int i=0;i<4;++i)
    pk[i] = (u32)(unsigned short)f2bfs(xn[2*i]) |
            ((u32)(unsigned short)f2bfs(xn[2*i+1]) << 16);
  #pragma unroll
  for(int i=0;i<4;++i) pq[i] = __shfl_xor((int)pk[i], 4);
  float px[8];
  #pragma unroll
  for(int i=0;i<4;++i){
    px[2*i]   = bf2f(__builtin_bit_cast(bf16,(short)(pq[i] & 0xffff)));
    px[2*i+1] = bf2f(__builtin_bit_cast(bf16,(short)(pq[i] >> 16)));
  }
  const float2* tb = tab + s*32 + (c & 3)*8;
  float qs = isK ? 1.f : 0.18033688f;
  bf16x8 o;
  #pragma unroll
  for(int i=0;i<8;++i){
    float2 cs = tb[i];
    float r = (c < 4) ? (xn[i]*cs.x - px[i]*cs.y) : (px[i]*cs.y + xn[i]*cs.x);
    o[i] = f2bfs(r*qs);
  }
  *(bf16x8*)p = o;
}

// ---------------- 8-phase 256x256 GEMM (T2+T3+T4+T5) — R12 config ----------------
#define LDA8(M,KH) dsr128(&Ah[((M)*16 + l15)*64 + ((((KH)*4 + l4) ^ l7))*8])
#define PHASE8(M0, STAGE_STMT, GATE_STMT) do{ \
  bf16x8 a0k0 = LDA8(M0,0), a0k1 = LDA8(M0,1), a1k0 = LDA8(M0+1,0), a1k1 = LDA8(M0+1,1); \
  STAGE_STMT; \
  __builtin_amdgcn_s_barrier(); \
  asm volatile("s_waitcnt lgkmcnt(0)" ::: "memory"); \
  __builtin_amdgcn_sched_barrier(0); \
  __builtin_amdgcn_s_setprio(1); \
  acc[M0][0]=mfma16(a0k0,bfrag[0][0],acc[M0][0]); \
  acc[M0][1]=mfma16(a0k0,bfrag[1][0],acc[M0][1]); \
  acc[M0][2]=mfma16(a0k0,bfrag[2][0],acc[M0][2]); \
  acc[M0][3]=mfma16(a0k0,bfrag[3][0],acc[M0][3]); \
  acc[M0+1][0]=mfma16(a1k0,bfrag[0][0],acc[M0+1][0]); \
  acc[M0+1][1]=mfma16(a1k0,bfrag[1][0],acc[M0+1][1]); \
  acc[M0+1][2]=mfma16(a1k0,bfrag[2][0],acc[M0+1][2]); \
  acc[M0+1][3]=mfma16(a1k0,bfrag[3][0],acc[M0+1][3]); \
  acc[M0][0]=mfma16(a0k1,bfrag[0][1],acc[M0][0]); \
  acc[M0][1]=mfma16(a0k1,bfrag[1][1],acc[M0][1]); \
  acc[M0][2]=mfma16(a0k1,bfrag[2][1],acc[M0][2]); \
  acc[M0][3]=mfma16(a0k1,bfrag[3][1],acc[M0][3]); \
  acc[M0+1][0]=mfma16(a1k1,bfrag[0][1],acc[M0+1][0]); \
  acc[M0+1][1]=mfma16(a1k1,bfrag[1][1],acc[M0+1][1]); \
  acc[M0+1][2]=mfma16(a1k1,bfrag[2][1],acc[M0+1][2]); \
  acc[M0+1][3]=mfma16(a1k1,bfrag[3][1],acc[M0+1][3]); \
  __builtin_amdgcn_s_setprio(0); \
  GATE_STMT; \
  __builtin_amdgcn_s_barrier(); }while(0)

template<int MODE>
__global__ __launch_bounds__(512, 2) void k_gemm8(
    const bf16* __restrict__ A, int lda,
    const bf16* __restrict__ BT, int ldb,
    const float* __restrict__ bias1, int K,
    const float* __restrict__ res, const float* __restrict__ gate,
    void* __restrict__ outp, int ldo)
{
  alignas(16) __shared__ short AH[2][2][128*64];
  alignas(16) __shared__ short BH[2][2][128*64];

  const int tid = threadIdx.x;
  const int lane = tid & 63, wid = tid >> 6;
  const int wm = wid >> 2, wn = wid & 3;
  const int l15 = lane & 15, l4 = lane >> 4;
  const int l7 = l15 & 7;
  const int brow = blockIdx.x * 256;
  const int bcol = blockIdx.y * 256;

  const int sr0 = tid >> 3;
  const int sr1 = sr0 + 64;
  const int sc  = ((tid & 7) ^ (sr0 & 7)) * 8;

  const bf16* Abase = A  + (size_t)brow*lda;
  const bf16* Bbase = BT + (size_t)bcol*ldb;

  auto stageA = [&](int t, int h){
    int d = t & 1;
    const bf16* g = Abase + (size_t)(h*128)*lda + t*64;
    gload16(g + (size_t)sr0*lda + sc, &AH[d][h][tid*8]);
    gload16(g + (size_t)sr1*lda + sc, &AH[d][h][(tid+512)*8]);
  };
  auto stageB = [&](int t, int h){
    int d = t & 1;
    const bf16* g = Bbase + (size_t)(h*128)*ldb + t*64;
    gload16(g + (size_t)sr0*ldb + sc, &BH[d][h][tid*8]);
    gload16(g + (size_t)sr1*ldb + sc, &BH[d][h][(tid+512)*8]);
  };

  f32x4 acc[8][4];
  f32x4 zero4 = {0.f,0.f,0.f,0.f};
  #pragma unroll
  for(int m=0;m<8;++m)
    #pragma unroll
    for(int n=0;n<4;++n) acc[m][n] = zero4;

  const int NT = K >> 6;
  stageA(0,0); stageA(0,1); stageB(0,0); stageB(0,1);
  stageB(1,0); stageB(1,1);
  asm volatile("s_waitcnt vmcnt(4)" ::: "memory");
  __builtin_amdgcn_sched_barrier(0);
  __builtin_amdgcn_s_barrier();

  const int bhsel = wn >> 1, brB = (wn & 1)*64;
  bf16x8 bfrag[4][2];

  for(int t=0; t<NT; ++t){
    const int d = t & 1;
    const short* Ah = AH[d][wm];
    const short* Bh = BH[d][bhsel];
    #pragma unroll
    for(int n=0;n<4;++n){
      int r = brB + n*16 + l15;
      bfrag[n][0] = dsr128(&Bh[r*64 + ((l4     ^ l7))*8]);
      bfrag[n][1] = dsr128(&Bh[r*64 + (((4|l4) ^ l7))*8]);
    }
    PHASE8(0, if(t+1 < NT) stageA(t+1,0), );
    PHASE8(2, if(t+1 < NT) stageA(t+1,1), );
    PHASE8(4, if(t+2 < NT) stageB(t+2,0), );
    PHASE8(6, if(t+2 < NT) stageB(t+2,1),
           asm volatile("s_waitcnt vmcnt(4)" ::: "memory");
           __builtin_amdgcn_sched_barrier(0) );
  }

  #pragma unroll
  for(int m=0;m<8;++m)
    #pragma unroll
    for(int n=0;n<4;++n)
      #pragma unroll
      for(int j=0;j<4;++j){
        int r  = brow + wm*128 + m*16 + l4*4 + j;
        int cc = bcol + wn*64  + n*16 + l15;
        float v = acc[m][n][j] + bias1[cc];
        if constexpr (MODE==0){
          ((bf16*)outp)[(size_t)r*ldo + cc] = f2bf(v);
        } else {
          int b = r >> 10;
          ((float*)outp)[(size_t)r*ldo + cc] =
              res[(size_t)r*Dd + cc] + gate[(size_t)b*ADA_LD + cc]*v;
        }
      }
}

// ---------------- dual-B SwiGLU GEMM: 4-buffer frag-pipelined ------
// 128x64 tile, BK=32. Step t: {issue STAGE(t+3); ds_read frags[t+1]->NXT;
// MFMA on CUR (no wait: completed prior step); lgkmcnt(0); vmcnt(4|0);
// barrier}. LDS 64KB -> 2 blocks/CU. nk must be even and >= 4 (nk=32).
__global__ __launch_bounds__(256, 2) void k_gemm3(
    const bf16* __restrict__ A, int lda,
    const bf16* __restrict__ BT, long long b2off, int ldb,
    const float* __restrict__ bias1, const float* __restrict__ bias2,
    int K, bf16* __restrict__ outp, int ldo)
{
  alignas(16) __shared__ short As[4][128*32];
  alignas(16) __shared__ short Bs[4][64*32];
  alignas(16) __shared__ short Bs2[4][64*32];

  int tid = threadIdx.x;
  int lane = tid & 63, wid = tid >> 6;
  int wm = wid >> 1, wn = wid & 1;
  int l15 = lane & 15, l4 = lane >> 4;
  int brow = blockIdx.x * 128;
  int bcol = blockIdx.y * 64;

  int r0 = tid >> 2, s0 = tid & 3;
  int r1 = r0 + 64;
  int k80 = s0 ^ ((r0 >> 1) & 3);
  int k81 = s0 ^ ((r1 >> 1) & 3);

  const bf16* a0 = A  + (size_t)(brow+r0)*lda + k80*8;
  const bf16* a1 = A  + (size_t)(brow+r1)*lda + k81*8;
  const bf16* b0 = BT + (size_t)(bcol+r0)*ldb + k80*8;

  f32x4 zero4 = {0.f,0.f,0.f,0.f};
  f32x4 acc[4][2], acc2[4][2];
  #pragma unroll
  for(int m=0;m<4;++m)
    #pragma unroll
    for(int n=0;n<2;++n){ acc[m][n]=zero4; acc2[m][n]=zero4; }

  auto STAGE = [&](int kt, int bi){
    int ko = kt << 5;
    gload16(a0 + ko, &As[bi][tid*8]);
    gload16(a1 + ko, &As[bi][(tid+256)*8]);
    gload16(b0 + ko, &Bs[bi][tid*8]);
    gload16(b0 + b2off + ko, &Bs2[bi][tid*8]);
  };

  // constant per-thread fragment offsets
  int arr[4], asl[4];
  #pragma unroll
  for(int m=0;m<4;++m){
    arr[m] = wm*64 + m*16 + l15;
    asl[m] = l4 ^ ((arr[m] >> 1) & 3);
  }
  int brr[2], bsl[2];
  #pragma unroll
  for(int n=0;n<2;++n){
    brr[n] = wn*32 + n*16 + l15;
    bsl[n] = l4 ^ ((brr[n] >> 1) & 3);
  }

  const int nk = K >> 5;   // 32: even, >= 4
  // prologue: 3 tiles staged; stages 0,1 landed (12 -> 4 in flight)
  STAGE(0, 0); STAGE(1, 1); STAGE(2, 2);
  asm volatile("s_waitcnt vmcnt(4)" ::: "memory");
  __builtin_amdgcn_sched_barrier(0);
  __builtin_amdgcn_s_barrier();

  bf16x8 afA[4], bfrA[2], bfr2A[2];
  bf16x8 afB[4], bfrB[2], bfr2B[2];

  // frags[0] -> A
  #pragma unroll
  for(int m=0;m<4;++m) afA[m] = dsr128(&As[0][arr[m]*32 + asl[m]*8]);
  #pragma unroll
  for(int n=0;n<2;++n){
    bfrA[n]  = dsr128(&Bs[0][brr[n]*32 + bsl[n]*8]);
    bfr2A[n] = dsr128(&Bs2[0][brr[n]*32 + bsl[n]*8]);
  }
  asm volatile("s_waitcnt lgkmcnt(0)" ::: "memory");
  __builtin_amdgcn_sched_barrier(0);

#define G3_BODY(T, afC, bfrC, bfr2C, afN, bfrN, bfr2N) do{                 \
    if((T)+3 < nk) STAGE((T)+3, ((T)+3)&3);                                \
    if((T)+1 < nk){                                                        \
      const int nb = ((T)+1)&3;                                            \
      _Pragma("unroll")                                                    \
      for(int m=0;m<4;++m) afN[m] = dsr128(&As[nb][arr[m]*32 + asl[m]*8]); \
      _Pragma("unroll")                                                    \
      for(int n=0;n<2;++n){                                                \
        bfrN[n]  = dsr128(&Bs[nb][brr[n]*32 + bsl[n]*8]);                  \
        bfr2N[n] = dsr128(&Bs2[nb][brr[n]*32 + bsl[n]*8]);                 \
      }                                                                    \
    }                                                                      \
    __builtin_amdgcn_s_setprio(1);                                         \
    _Pragma("unroll")                                                      \
    for(int m=0;m<4;++m){                                                  \
      acc[m][0]  = mfma16(afC[m], bfrC[0],  acc[m][0]);                    \
      acc2[m][0] = mfma16(afC[m], bfr2C[0], acc2[m][0]);                   \
      acc[m][1]  = mfma16(afC[m], bfrC[1],  acc[m][1]);                    \
      acc2[m][1] = mfma16(afC[m], bfr2C[1], acc2[m][1]);                   \
    }                                                                      \
    __builtin_amdgcn_s_setprio(0);                                         \
    asm volatile("s_waitcnt lgkmcnt(0)" ::: "memory");                     \
    __builtin_amdgcn_sched_barrier(0);                                     \
    if((T)+3 < nk){ asm volatile("s_waitcnt vmcnt(4)" ::: "memory"); }     \
    else          { asm volatile("s_waitcnt vmcnt(0)" ::: "memory"); }     \
    __builtin_amdgcn_sched_barrier(0);                                     \
    __builtin_amdgcn_s_barrier();                                          \
  }while(0)

  for(int t=0; t<nk; t+=2){
    G3_BODY(t,   afA, bfrA, bfr2A, afB, bfrB, bfr2B);
    G3_BODY(t+1, afB, bfrB, bfr2B, afA, bfrA, bfr2A);
  }
#undef G3_BODY

  #pragma unroll
  for(int m=0;m<4;++m)
    #pragma unroll
    for(int n=0;n<2;++n)
      #pragma unroll
      for(int j=0;j<4;++j){
        int r  = brow + wm*64 + m*16 + l4*4 + j;
        int cc = bcol + wn*32 + n*16 + l15;
        float o = 0.f;
        if(cc < MLPH){
          float v1 = acc[m][n][j] + bias1[cc];
          float v2 = acc2[m][n][j] + bias2[cc];
          o = (v1/(1.f+__expf(-v1)))*v2;
        }
        outp[(size_t)r*ldo + cc] = f2bf(o);
      }
}

// ---------------- flash attention: hi-batched (R15) ----------------
__global__ __launch_bounds__(256) void k_attn(const bf16* __restrict__ qkv, bf16* __restrict__ obuf){
  alignas(16) __shared__ short Ks[64*64];
  alignas(16) __shared__ short VTs[64*64];
  alignas(16) __shared__ short Ps[128*64];

  int flatb = blockIdx.x;
  int low3 = flatb & 7;
  int rest = flatb >> 3;
  int qb   = rest & 7;
  int bh   = ((rest >> 3) << 3) | low3;
  int b = bh >> 4, h = bh & 15;

  int tid = threadIdx.x;
  int lane = tid & 63, w = tid >> 6;
  int l15 = lane & 15, l4 = lane >> 4;

  const bf16* base = qkv + (size_t)b*Ss*3072 + h*HD;

  bf16x8 aq[2][2];
  #pragma unroll
  for(int hi=0;hi<2;++hi)
    #pragma unroll
    for(int hf=0;hf<2;++hf)
      aq[hi][hf] = *(const bf16x8*)(base +
          (size_t)(qb*128 + w*32 + hi*16 + l15)*3072 + hf*32 + l4*8);

  int r0 = tid >> 3, c0 = tid & 7;
  int khcol = (c0 ^ (r0 & 7)) * 8;
  bf16x8 kreg[2], vreg[2];
  #pragma unroll
  for(int ch=0; ch<2; ++ch){
    int rr = r0 + ch*32;
    kreg[ch] = *(const bf16x8*)(base + Dd   + (size_t)rr*3072 + khcol);
    vreg[ch] = *(const bf16x8*)(base + 2*Dd + (size_t)rr*3072 + c0*8);
  }

  f32x4 zero4 = {0.f,0.f,0.f,0.f};
  f32x4 acc_o[2][4];
  float mrow[2], lrow[2];
  #pragma unroll
  for(int hi=0;hi<2;++hi){
    mrow[hi] = -1e30f; lrow[hi] = 0.f;
    #pragma unroll
    for(int an=0;an<4;++an) acc_o[hi][an] = zero4;
  }

  const float THR = 11.54f;

  for(int kb=0; kb<Ss/64; ++kb){
    if(kb) __syncthreads();
    #pragma unroll
    for(int ch=0; ch<2; ++ch){
      *(bf16x8*)&Ks[(tid + ch*256)*8] = kreg[ch];
      int vr = r0 + ch*32;
      #pragma unroll
      for(int i=0;i<8;++i){
        int g = i ^ c0;
        VTs[(c0*8 + i)*64 + (vr ^ (g<<3))] = vreg[ch][i];
      }
    }
    if(kb+1 < Ss/64){
      #pragma unroll
      for(int ch=0; ch<2; ++ch){
        int rr = (kb+1)*64 + r0 + ch*32;
        kreg[ch] = *(const bf16x8*)(base + Dd   + (size_t)rr*3072 + khcol);
        vreg[ch] = *(const bf16x8*)(base + 2*Dd + (size_t)rr*3072 + c0*8);
      }
    }
    __syncthreads();

    bf16x8 kf[4][2];
    #pragma unroll
    for(int an=0;an<4;++an){
      int R = an*16 + l15;
      kf[an][0] = *(const bf16x8*)&Ks[R*64 + ((l4     ^ (R&7)))*8];
      kf[an][1] = *(const bf16x8*)&Ks[R*64 + (((4|l4) ^ (R&7)))*8];
    }
    f32x4 sacc[2][4];
    #pragma unroll
    for(int hi=0;hi<2;++hi)
      #pragma unroll
      for(int an=0;an<4;++an) sacc[hi][an] = zero4;
    __builtin_amdgcn_s_setprio(1);
    #pragma unroll
    for(int an=0;an<4;++an){
      sacc[0][an] = mfma16(kf[an][0], aq[0][0], sacc[0][an]);
      sacc[1][an] = mfma16(kf[an][0], aq[1][0], sacc[1][an]);
    }
    #pragma unroll
    for(int an=0;an<4;++an){
      sacc[0][an] = mfma16(kf[an][1], aq[0][1], sacc[0][an]);
      sacc[1][an] = mfma16(kf[an][1], aq[1][1], sacc[1][an]);
    }
    __builtin_amdgcn_s_setprio(0);

    #pragma unroll
    for(int hi=0; hi<2; ++hi){
      float mx = -1e30f;
      #pragma unroll
      for(int an=0;an<4;++an)
        #pragma unroll
        for(int j=0;j<4;++j) mx = fmaxf(mx, sacc[hi][an][j]);
      mx = fmaxf(mx, __shfl_xor(mx, 16));
      mx = fmaxf(mx, __shfl_xor(mx, 32));
      bool grow = mx > mrow[hi] + THR;
      if(__any(grow)){
        float mnew = fmaxf(mrow[hi], mx);
        float corr = exp2f(mrow[hi] - mnew);
        mrow[hi] = mnew;
        lrow[hi] *= corr;
        float cj[4];
        #pragma unroll
        for(int j=0;j<4;++j) cj[j] = __shfl(corr, l4*4 + j);
        #pragma unroll
        for(int an=0;an<4;++an)
          #pragma unroll
          for(int j=0;j<4;++j) acc_o[hi][an][j] *= cj[j];
      }
      float psum = 0.f;
      #pragma unroll
      for(int an=0;an<4;++an)
        #pragma unroll
        for(int j=0;j<4;++j){
          float pv = exp2f(sacc[hi][an][j] - mrow[hi]);
          sacc[hi][an][j] = pv; psum += pv;
        }
      psum += __shfl_xor(psum, 16);
      psum += __shfl_xor(psum, 32);
      lrow[hi] += psum;

      int prow = w*32 + hi*16 + l15;
      int pg = (l15 & 7) << 3;
      #pragma unroll
      for(int an=0;an<4;++an)
        #pragma unroll
        for(int j=0;j<4;++j)
          Ps[prow*64 + ((an*16 + l4*4 + j) ^ pg)] = f2bfs(sacc[hi][an][j]);
    }

    int pgme = (l15 & 7) << 3;
    bf16x8 pa[2][2];
    #pragma unroll
    for(int hi=0;hi<2;++hi){
      int prow = w*32 + hi*16 + l15;
      pa[hi][0] = *(const bf16x8*)&Ps[prow*64 + ((l4*8)      ^ pgme)];
      pa[hi][1] = *(const bf16x8*)&Ps[prow*64 + ((32 + l4*8) ^ pgme)];
    }
    bf16x8 vf[4][2];
    #pragma unroll
    for(int an2=0;an2<4;++an2){
      int dR = an2*16 + l15;
      int g = ((dR & 7) ^ ((dR >> 3) & 7)) << 3;
      vf[an2][0] = *(const bf16x8*)&VTs[dR*64 + ((l4*8)      ^ g)];
      vf[an2][1] = *(const bf16x8*)&VTs[dR*64 + ((32 + l4*8) ^ g)];
    }
    __builtin_amdgcn_s_setprio(1);
    #pragma unroll
    for(int an2=0;an2<4;++an2){
      acc_o[0][an2] = mfma16(pa[0][0], vf[an2][0], acc_o[0][an2]);
      acc_o[1][an2] = mfma16(pa[1][0], vf[an2][0], acc_o[1][an2]);
    }
    #pragma unroll
    for(int an2=0;an2<4;++an2){
      acc_o[0][an2] = mfma16(pa[0][1], vf[an2][1], acc_o[0][an2]);
      acc_o[1][an2] = mfma16(pa[1][1], vf[an2][1], acc_o[1][an2]);
    }
    __builtin_amdgcn_s_setprio(0);
  }

  #pragma unroll
  for(int hi=0;hi<2;++hi){
    float lr[4];
    #pragma unroll
    for(int j=0;j<4;++j) lr[j] = __shfl(lrow[hi], l4*4 + j);
    #pragma unroll
    for(int an2=0;an2<4;++an2)
      #pragma unroll
      for(int j=0;j<4;++j){
        int r = qb*128 + w*32 + hi*16 + l4*4 + j;
        float ov = acc_o[hi][an2][j] / lr[j];
        obuf[((size_t)b*Ss + r)*Dd + h*HD + an2*16 + l15] = f2bf(ov);
      }
  }
}

} // namespace

extern "C" void kernel_launch(void* const* d_in, const int* in_sizes, int n_in,
                              void* d_out, int out_size, void* d_ws, size_t ws_size,
                              hipStream_t stream){
  const float* x      = (const float*)d_in[0];
  const float* c      = (const float*)d_in[1];
  const float* w_qkv  = (const float*)d_in[2];
  const float* b_qkv  = (const float*)d_in[3];
  const float* w_proj = (const float*)d_in[4];
  const float* b_proj = (const float*)d_in[5];
  const float* w12    = (const float*)d_in[6];
  const float* b12    = (const float*)d_in[7];
  const float* w3     = (const float*)d_in[8];
  const float* b3     = (const float*)d_in[9];
  const float* w_ada  = (const float*)d_in[10];
  const float* b_ada  = (const float*)d_in[11];
  const float* n1w    = (const float*)d_in[12];
  const float* n2w    = (const float*)d_in[13];
  const float* qnw    = (const float*)d_in[14];
  const float* knw    = (const float*)d_in[15];
  float* out = (float*)d_out;
  (void)in_sizes; (void)n_in; (void)out_size;

  constexpr size_t WS_NEED = 227254272ull;
  if (ws_size < WS_NEED) return;

  char* ws = (char*)d_ws;
  float*  silu_c = (float*)(ws + 0);
  float*  ada    = (float*)(ws + 65536);
  float2* ropet  = (float2*)(ws + 458752);
  bf16*   wqkvT  = (bf16*)(ws + 720896);
  bf16*   wprojT = (bf16*)(ws + 7012352);
  bf16*   w12T   = (bf16*)(ws + 9109504);
  bf16*   w3T    = (bf16*)(ws + 20291584);
  bf16*   hbuf   = (bf16*)(ws + 25927680);
  bf16*   qkvb   = (bf16*)(ws + 59482112);
  float*  xmid   = (float*)(ws + 160145408);
  bf16*   obuf   = hbuf;
  bf16*   h2     = hbuf;
  bf16*   mlpmid = qkvb;

  k_silu<<<64,256,0,stream>>>(c, silu_c, Bb*Dd);
  k_rope_tab<<<128,256,0,stream>>>(ropet);
  k_ada<<<96,256,0,stream>>>(silu_c, w_ada, b_ada, ada);
  k_transpose<<<dim3(32,96),256,0,stream>>>(w_qkv, wqkvT, 1024, 3072, 1024);
  k_transpose<<<dim3(32,32),256,0,stream>>>(w_proj, wprojT, 1024, 1024, 1024);
  k_transpose<<<dim3(32,171),256,0,stream>>>(w12, w12T, 1024, 5460, 1024);
  k_transpose<<<dim3(86,32),256,0,stream>>>(w3, w3T, 2730, 1024, 2752);

  // attention branch
  k_norm_mod<<<NR,256,0,stream>>>(x, n1w, ada + 0, ada + 1024, hbuf);
  k_gemm8<0><<<dim3(64,12),512,0,stream>>>(hbuf,1024, wqkvT,1024,
      b_qkv, 1024, nullptr,nullptr, qkvb,3072);
  k_qknorm<<<NR,256,0,stream>>>(qkvb, qnw, knw, ropet);
  k_attn<<<2048,256,0,stream>>>(qkvb, obuf);
  k_gemm8<1><<<dim3(64,4),512,0,stream>>>(obuf,1024, wprojT,1024,
      b_proj, 1024, x, ada + 2048, xmid,1024);

  // MLP branch
  k_norm_mod<<<NR,256,0,stream>>>(xmid, n2w, ada + 3072, ada + 4096, h2);
  k_gemm3<<<dim3(128,43),256,0,stream>>>(h2,1024, w12T,(long long)MLPH*1024,1024,
      b12, b12 + MLPH, 1024, mlpmid, MLPH_PAD);
  k_gemm8<1><<<dim3(64,4),512,0,stream>>>(mlpmid,MLPH_PAD, w3T,MLPH_PAD,
      b3, MLPH_PAD, xmid, ada + 5120, out,1024);
}

// Round 18
// 861.608 us; speedup vs baseline: 1.0327x; 1.0327x over previous
//
#include <hip/hip_runtime.h>
#include <hip/hip_bf16.h>
#include <math.h>

namespace {

constexpr int Bb = 16;
constexpr int Ss = 1024;
constexpr int Dd = 1024;
constexpr int Hh = 16;
constexpr int HD = 64;
constexpr int MLPH = 2730;
constexpr int MLPH_PAD = 2752;
constexpr int ADA_LD = 6144;
constexpr int NR = Bb * Ss; // 16384 rows

typedef __attribute__((ext_vector_type(8))) short bf16x8;
typedef __attribute__((ext_vector_type(4))) float f32x4;
typedef __hip_bfloat16 bf16;
typedef unsigned int u32;

__device__ __forceinline__ float bf2f(bf16 v){ return __bfloat162float(v); }
__device__ __forceinline__ bf16 f2bf(float v){ return __float2bfloat16(v); }
__device__ __forceinline__ short f2bfs(float v){ bf16 t = __float2bfloat16(v); return __builtin_bit_cast(short, t); }

__device__ __forceinline__ f32x4 mfma16(bf16x8 a, bf16x8 b, f32x4 c){
  return __builtin_amdgcn_mfma_f32_16x16x32_bf16(a, b, c, 0, 0, 0);
}

// async global->LDS, 16B per lane; LDS dest linear (wave base + lane*16)
__device__ __forceinline__ void gload16(const void* g, void* l){
  __builtin_amdgcn_global_load_lds(
      (const __attribute__((address_space(1))) u32*)g,
      (__attribute__((address_space(3))) u32*)l, 16, 0, 0);
}

// opaque LDS b128 read (ordering carried by explicit waitcnt fences)
__device__ __forceinline__ bf16x8 dsr128(const short* p){
  f32x4 r;
  asm volatile("ds_read_b128 %0, %1" : "=v"(r) : "v"((u32)(size_t)p));
  return __builtin_bit_cast(bf16x8, r);
}

// ---------------- small kernels ----------------

__global__ void k_silu(const float* __restrict__ c, float* __restrict__ out, int n){
  int i = blockIdx.x*256 + threadIdx.x;
  if(i < n){ float v = c[i]; out[i] = v / (1.f + __expf(-v)); }
}

__global__ __launch_bounds__(256) void k_ada(const float* __restrict__ sc,
    const float* __restrict__ w, const float* __restrict__ bias, float* __restrict__ ada){
  __shared__ float red[4][Bb][64];
  int tid = threadIdx.x;
  int jj = tid & 63, ks = tid >> 6;
  int j = blockIdx.x*64 + jj;
  float acc[Bb];
  #pragma unroll
  for(int b=0;b<Bb;++b) acc[b] = 0.f;
  for(int k=ks*256; k<ks*256+256; ++k){
    float wv = w[(size_t)k*ADA_LD + j];
    #pragma unroll
    for(int b=0;b<Bb;++b) acc[b] += sc[b*Dd + k] * wv;
  }
  #pragma unroll
  for(int b=0;b<Bb;++b) red[ks][b][jj] = acc[b];
  __syncthreads();
  #pragma unroll
  for(int rep=0;rep<4;++rep){
    int idx = rep*256 + tid;
    int b = idx >> 6, j2 = idx & 63;
    float s = red[0][b][j2]+red[1][b][j2]+red[2][b][j2]+red[3][b][j2];
    ada[(size_t)b*ADA_LD + blockIdx.x*64 + j2] = s + bias[blockIdx.x*64 + j2];
  }
}

__global__ void k_rope_tab(float2* __restrict__ tab){
  int i = blockIdx.x*256 + threadIdx.x;
  int s = i >> 5, f = i & 31;
  float inv = powf(10000.f, -((float)(2*f)) / 64.f);
  float fr = (float)s * inv;
  float sv, cv;
  sincosf(fr, &sv, &cv);
  tab[i] = make_float2(cv, sv);
}

// in f32 [R,C] -> out bf16 [C,Rpad], zero-filled for col in [R,Rpad)
__global__ void k_transpose(const float* __restrict__ in, bf16* __restrict__ out,
                            int R, int C, int Rpad){
  __shared__ short tile[32][33];
  int tx = threadIdx.x & 31, ty = threadIdx.x >> 5;
  int tr0 = blockIdx.x*32, tc0 = blockIdx.y*32;
  #pragma unroll
  for(int i=0;i<4;++i){
    int r = tr0 + ty + i*8, cc = tc0 + tx;
    short v = 0;
    if(r < R && cc < C) v = f2bfs(in[(size_t)r*C + cc]);
    tile[ty+i*8][tx] = v;
  }
  __syncthreads();
  #pragma unroll
  for(int i=0;i<4;++i){
    int oc = tc0 + ty + i*8;
    int orow = tr0 + tx;
    if(oc < C && orow < Rpad)
      out[(size_t)oc*Rpad + orow] = __builtin_bit_cast(bf16, tile[tx][ty+i*8]);
  }
}

// RMSNorm over D + adaLN modulate
__global__ __launch_bounds__(256) void k_norm_mod(const float* __restrict__ x,
    const float* __restrict__ w, const float* __restrict__ shift, const float* __restrict__ scale,
    bf16* __restrict__ out){
  int r = blockIdx.x;
  int b = r >> 10;
  int t = threadIdx.x;
  const float* xr = x + (size_t)r*Dd;
  float v[4]; float ss = 0.f;
  #pragma unroll
  for(int i=0;i<4;++i){
    float f = xr[t*4+i];
    v[i] = f; ss += f*f;
  }
  #pragma unroll
  for(int m=1;m<64;m<<=1) ss += __shfl_xor(ss, m);
  __shared__ float red[4];
  if((t & 63) == 0) red[t>>6] = ss;
  __syncthreads();
  float tot = red[0]+red[1]+red[2]+red[3];
  float rms = rsqrtf(tot * (1.f/Dd) + 1e-6f);
  #pragma unroll
  for(int i=0;i<4;++i){
    int ccol = t*4+i;
    float h = v[i]*rms*w[ccol];
    float scv = scale[(size_t)b*ADA_LD + ccol];
    float shv = shift[(size_t)b*ADA_LD + ccol];
    out[(size_t)r*Dd + ccol] = f2bf(h*(1.f+scv) + shv);
  }
}

// per-(b,s) RMSNorm(64)+RoPE for q,k of qkv, in place, vectorized.
// Q additionally scaled by 0.125*log2(e) (score scale folded; attn uses exp2).
__global__ __launch_bounds__(256) void k_qknorm(bf16* __restrict__ qkv,
    const float* __restrict__ qw, const float* __restrict__ kw,
    const float2* __restrict__ tab){
  int bs = blockIdx.x;
  int s = bs & (Ss-1);
  int tid = threadIdx.x;
  int wv = tid >> 6, lane = tid & 63;
  int isK = wv >> 1;
  int chunk = (wv & 1)*64 + lane;
  int c = chunk & 7;
  int h = chunk >> 3;
  int dih = c*8;
  bf16* p = qkv + (size_t)bs*3072 + isK*Dd + h*HD + dih;
  bf16x8 v = *(const bf16x8*)p;
  float x[8]; float ss = 0.f;
  #pragma unroll
  for(int i=0;i<8;++i){ x[i] = bf2f(__builtin_bit_cast(bf16,(short)v[i])); ss += x[i]*x[i]; }
  ss += __shfl_xor(ss,1); ss += __shfl_xor(ss,2); ss += __shfl_xor(ss,4);
  float rms = rsqrtf(ss*(1.f/HD) + 1e-6f);
  const float* wn = isK ? kw : qw;
  float xn[8];
  #pragma unroll
  for(int i=0;i<8;++i) xn[i] = x[i]*rms*wn[dih+i];
  u32 pk[4], pq[4];
  #pragma unroll
  for(int i=0;i<4;++i)
    pk[i] = (u32)(unsigned short)f2bfs(xn[2*i]) |
            ((u32)(unsigned short)f2bfs(xn[2*i+1]) << 16);
  #pragma unroll
  for(int i=0;i<4;++i) pq[i] = __shfl_xor((int)pk[i], 4);
  float px[8];
  #pragma unroll
  for(int i=0;i<4;++i){
    px[2*i]   = bf2f(__builtin_bit_cast(bf16,(short)(pq[i] & 0xffff)));
    px[2*i+1] = bf2f(__builtin_bit_cast(bf16,(short)(pq[i] >> 16)));
  }
  const float2* tb = tab + s*32 + (c & 3)*8;
  float qs = isK ? 1.f : 0.18033688f;
  bf16x8 o;
  #pragma unroll
  for(int i=0;i<8;++i){
    float2 cs = tb[i];
    float r = (c < 4) ? (xn[i]*cs.x - px[i]*cs.y) : (px[i]*cs.y + xn[i]*cs.x);
    o[i] = f2bfs(r*qs);
  }
  *(bf16x8*)p = o;
}

// ---------------- 8-phase 256x256 GEMM (T2+T3+T4+T5) — R12 config ----------------
#define LDA8(M,KH) dsr128(&Ah[((M)*16 + l15)*64 + ((((KH)*4 + l4) ^ l7))*8])
#define PHASE8(M0, STAGE_STMT, GATE_STMT) do{ \
  bf16x8 a0k0 = LDA8(M0,0), a0k1 = LDA8(M0,1), a1k0 = LDA8(M0+1,0), a1k1 = LDA8(M0+1,1); \
  STAGE_STMT; \
  __builtin_amdgcn_s_barrier(); \
  asm volatile("s_waitcnt lgkmcnt(0)" ::: "memory"); \
  __builtin_amdgcn_sched_barrier(0); \
  __builtin_amdgcn_s_setprio(1); \
  acc[M0][0]=mfma16(a0k0,bfrag[0][0],acc[M0][0]); \
  acc[M0][1]=mfma16(a0k0,bfrag[1][0],acc[M0][1]); \
  acc[M0][2]=mfma16(a0k0,bfrag[2][0],acc[M0][2]); \
  acc[M0][3]=mfma16(a0k0,bfrag[3][0],acc[M0][3]); \
  acc[M0+1][0]=mfma16(a1k0,bfrag[0][0],acc[M0+1][0]); \
  acc[M0+1][1]=mfma16(a1k0,bfrag[1][0],acc[M0+1][1]); \
  acc[M0+1][2]=mfma16(a1k0,bfrag[2][0],acc[M0+1][2]); \
  acc[M0+1][3]=mfma16(a1k0,bfrag[3][0],acc[M0+1][3]); \
  acc[M0][0]=mfma16(a0k1,bfrag[0][1],acc[M0][0]); \
  acc[M0][1]=mfma16(a0k1,bfrag[1][1],acc[M0][1]); \
  acc[M0][2]=mfma16(a0k1,bfrag[2][1],acc[M0][2]); \
  acc[M0][3]=mfma16(a0k1,bfrag[3][1],acc[M0][3]); \
  acc[M0+1][0]=mfma16(a1k1,bfrag[0][1],acc[M0+1][0]); \
  acc[M0+1][1]=mfma16(a1k1,bfrag[1][1],acc[M0+1][1]); \
  acc[M0+1][2]=mfma16(a1k1,bfrag[2][1],acc[M0+1][2]); \
  acc[M0+1][3]=mfma16(a1k1,bfrag[3][1],acc[M0+1][3]); \
  __builtin_amdgcn_s_setprio(0); \
  GATE_STMT; \
  __builtin_amdgcn_s_barrier(); }while(0)

template<int MODE>
__global__ __launch_bounds__(512, 2) void k_gemm8(
    const bf16* __restrict__ A, int lda,
    const bf16* __restrict__ BT, int ldb,
    const float* __restrict__ bias1, int K,
    const float* __restrict__ res, const float* __restrict__ gate,
    void* __restrict__ outp, int ldo)
{
  alignas(16) __shared__ short AH[2][2][128*64];
  alignas(16) __shared__ short BH[2][2][128*64];

  const int tid = threadIdx.x;
  const int lane = tid & 63, wid = tid >> 6;
  const int wm = wid >> 2, wn = wid & 3;
  const int l15 = lane & 15, l4 = lane >> 4;
  const int l7 = l15 & 7;
  const int brow = blockIdx.x * 256;
  const int bcol = blockIdx.y * 256;

  const int sr0 = tid >> 3;
  const int sr1 = sr0 + 64;
  const int sc  = ((tid & 7) ^ (sr0 & 7)) * 8;

  const bf16* Abase = A  + (size_t)brow*lda;
  const bf16* Bbase = BT + (size_t)bcol*ldb;

  auto stageA = [&](int t, int h){
    int d = t & 1;
    const bf16* g = Abase + (size_t)(h*128)*lda + t*64;
    gload16(g + (size_t)sr0*lda + sc, &AH[d][h][tid*8]);
    gload16(g + (size_t)sr1*lda + sc, &AH[d][h][(tid+512)*8]);
  };
  auto stageB = [&](int t, int h){
    int d = t & 1;
    const bf16* g = Bbase + (size_t)(h*128)*ldb + t*64;
    gload16(g + (size_t)sr0*ldb + sc, &BH[d][h][tid*8]);
    gload16(g + (size_t)sr1*ldb + sc, &BH[d][h][(tid+512)*8]);
  };

  f32x4 acc[8][4];
  f32x4 zero4 = {0.f,0.f,0.f,0.f};
  #pragma unroll
  for(int m=0;m<8;++m)
    #pragma unroll
    for(int n=0;n<4;++n) acc[m][n] = zero4;

  const int NT = K >> 6;
  stageA(0,0); stageA(0,1); stageB(0,0); stageB(0,1);
  stageB(1,0); stageB(1,1);
  asm volatile("s_waitcnt vmcnt(4)" ::: "memory");
  __builtin_amdgcn_sched_barrier(0);
  __builtin_amdgcn_s_barrier();

  const int bhsel = wn >> 1, brB = (wn & 1)*64;
  bf16x8 bfrag[4][2];

  for(int t=0; t<NT; ++t){
    const int d = t & 1;
    const short* Ah = AH[d][wm];
    const short* Bh = BH[d][bhsel];
    #pragma unroll
    for(int n=0;n<4;++n){
      int r = brB + n*16 + l15;
      bfrag[n][0] = dsr128(&Bh[r*64 + ((l4     ^ l7))*8]);
      bfrag[n][1] = dsr128(&Bh[r*64 + (((4|l4) ^ l7))*8]);
    }
    PHASE8(0, if(t+1 < NT) stageA(t+1,0), );
    PHASE8(2, if(t+1 < NT) stageA(t+1,1), );
    PHASE8(4, if(t+2 < NT) stageB(t+2,0), );
    PHASE8(6, if(t+2 < NT) stageB(t+2,1),
           asm volatile("s_waitcnt vmcnt(4)" ::: "memory");
           __builtin_amdgcn_sched_barrier(0) );
  }

  #pragma unroll
  for(int m=0;m<8;++m)
    #pragma unroll
    for(int n=0;n<4;++n)
      #pragma unroll
      for(int j=0;j<4;++j){
        int r  = brow + wm*128 + m*16 + l4*4 + j;
        int cc = bcol + wn*64  + n*16 + l15;
        float v = acc[m][n][j] + bias1[cc];
        if constexpr (MODE==0){
          ((bf16*)outp)[(size_t)r*ldo + cc] = f2bf(v);
        } else {
          int b = r >> 10;
          ((float*)outp)[(size_t)r*ldo + cc] =
              res[(size_t)r*Dd + cc] + gate[(size_t)b*ADA_LD + cc]*v;
        }
      }
}

// ---------------- dual-B SwiGLU GEMM: 3-buffer counted-vmcnt (R16 best) ------
// 128x64 tile, BK=32; stage(t+2) stays in flight (vmcnt(4) gate, never 0
// mid-loop); opaque dsr128 frags + explicit lgkmcnt/sched fences.
// LDS 48KB -> 3 blocks/CU. Requires nk>=3 (only called with K=1024, nk=32).
__global__ __launch_bounds__(256, 2) void k_gemm3(
    const bf16* __restrict__ A, int lda,
    const bf16* __restrict__ BT, long long b2off, int ldb,
    const float* __restrict__ bias1, const float* __restrict__ bias2,
    int K, bf16* __restrict__ outp, int ldo)
{
  alignas(16) __shared__ short As[3][128*32];
  alignas(16) __shared__ short Bs[3][64*32];
  alignas(16) __shared__ short Bs2[3][64*32];

  int tid = threadIdx.x;
  int lane = tid & 63, wid = tid >> 6;
  int wm = wid >> 1, wn = wid & 1;
  int l15 = lane & 15, l4 = lane >> 4;
  int brow = blockIdx.x * 128;
  int bcol = blockIdx.y * 64;

  int r0 = tid >> 2, s0 = tid & 3;
  int r1 = r0 + 64;
  int k80 = s0 ^ ((r0 >> 1) & 3);
  int k81 = s0 ^ ((r1 >> 1) & 3);

  const bf16* a0 = A  + (size_t)(brow+r0)*lda + k80*8;
  const bf16* a1 = A  + (size_t)(brow+r1)*lda + k81*8;
  const bf16* b0 = BT + (size_t)(bcol+r0)*ldb + k80*8;

  f32x4 zero4 = {0.f,0.f,0.f,0.f};
  f32x4 acc[4][2], acc2[4][2];
  #pragma unroll
  for(int m=0;m<4;++m)
    #pragma unroll
    for(int n=0;n<2;++n){ acc[m][n]=zero4; acc2[m][n]=zero4; }

  auto STAGE = [&](int kt, int bi){
    int ko = kt << 5;
    gload16(a0 + ko, &As[bi][tid*8]);
    gload16(a1 + ko, &As[bi][(tid+256)*8]);
    gload16(b0 + ko, &Bs[bi][tid*8]);
    gload16(b0 + b2off + ko, &Bs2[bi][tid*8]);
  };

  const int nk = K >> 5;
  STAGE(0, 0);
  STAGE(1, 1);
  asm volatile("s_waitcnt vmcnt(4)" ::: "memory");
  __builtin_amdgcn_sched_barrier(0);
  __builtin_amdgcn_s_barrier();

  int arr[4], asl[4];
  #pragma unroll
  for(int m=0;m<4;++m){
    arr[m] = wm*64 + m*16 + l15;
    asl[m] = l4 ^ ((arr[m] >> 1) & 3);
  }
  int brr[2], bsl[2];
  #pragma unroll
  for(int n=0;n<2;++n){
    brr[n] = wn*32 + n*16 + l15;
    bsl[n] = l4 ^ ((brr[n] >> 1) & 3);
  }

  int bi = 0;
  for(int kt=0; kt<nk; ++kt){
    bool more = (kt+2) < nk;
    int bn = bi+2; if(bn >= 3) bn -= 3;
    if(more) STAGE(kt+2, bn);

    bf16x8 af[4], bfr[2], bfr2[2];
    #pragma unroll
    for(int m=0;m<4;++m) af[m] = dsr128(&As[bi][arr[m]*32 + asl[m]*8]);
    #pragma unroll
    for(int n=0;n<2;++n){
      bfr[n]  = dsr128(&Bs[bi][brr[n]*32 + bsl[n]*8]);
      bfr2[n] = dsr128(&Bs2[bi][brr[n]*32 + bsl[n]*8]);
    }
    asm volatile("s_waitcnt lgkmcnt(0)" ::: "memory");
    __builtin_amdgcn_sched_barrier(0);
    __builtin_amdgcn_s_setprio(1);
    #pragma unroll
    for(int m=0;m<4;++m){
      acc[m][0]  = mfma16(af[m], bfr[0],  acc[m][0]);
      acc2[m][0] = mfma16(af[m], bfr2[0], acc2[m][0]);
      acc[m][1]  = mfma16(af[m], bfr[1],  acc[m][1]);
      acc2[m][1] = mfma16(af[m], bfr2[1], acc2[m][1]);
    }
    __builtin_amdgcn_s_setprio(0);
    if(more){ asm volatile("s_waitcnt vmcnt(4)" ::: "memory"); }
    else    { asm volatile("s_waitcnt vmcnt(0)" ::: "memory"); }
    __builtin_amdgcn_sched_barrier(0);
    __builtin_amdgcn_s_barrier();
    ++bi; if(bi >= 3) bi = 0;
  }

  #pragma unroll
  for(int m=0;m<4;++m)
    #pragma unroll
    for(int n=0;n<2;++n)
      #pragma unroll
      for(int j=0;j<4;++j){
        int r  = brow + wm*64 + m*16 + l4*4 + j;
        int cc = bcol + wn*32 + n*16 + l15;
        float o = 0.f;
        if(cc < MLPH){
          float v1 = acc[m][n][j] + bias1[cc];
          float v2 = acc2[m][n][j] + bias2[cc];
          o = (v1/(1.f+__expf(-v1)))*v2;
        }
        outp[(size_t)r*ldo + cc] = f2bf(o);
      }
}

// ---------------- flash attention: hi-batched (R15) ----------------
__global__ __launch_bounds__(256) void k_attn(const bf16* __restrict__ qkv, bf16* __restrict__ obuf){
  alignas(16) __shared__ short Ks[64*64];
  alignas(16) __shared__ short VTs[64*64];
  alignas(16) __shared__ short Ps[128*64];

  int flatb = blockIdx.x;
  int low3 = flatb & 7;
  int rest = flatb >> 3;
  int qb   = rest & 7;
  int bh   = ((rest >> 3) << 3) | low3;
  int b = bh >> 4, h = bh & 15;

  int tid = threadIdx.x;
  int lane = tid & 63, w = tid >> 6;
  int l15 = lane & 15, l4 = lane >> 4;

  const bf16* base = qkv + (size_t)b*Ss*3072 + h*HD;

  bf16x8 aq[2][2];
  #pragma unroll
  for(int hi=0;hi<2;++hi)
    #pragma unroll
    for(int hf=0;hf<2;++hf)
      aq[hi][hf] = *(const bf16x8*)(base +
          (size_t)(qb*128 + w*32 + hi*16 + l15)*3072 + hf*32 + l4*8);

  int r0 = tid >> 3, c0 = tid & 7;
  int khcol = (c0 ^ (r0 & 7)) * 8;
  bf16x8 kreg[2], vreg[2];
  #pragma unroll
  for(int ch=0; ch<2; ++ch){
    int rr = r0 + ch*32;
    kreg[ch] = *(const bf16x8*)(base + Dd   + (size_t)rr*3072 + khcol);
    vreg[ch] = *(const bf16x8*)(base + 2*Dd + (size_t)rr*3072 + c0*8);
  }

  f32x4 zero4 = {0.f,0.f,0.f,0.f};
  f32x4 acc_o[2][4];
  float mrow[2], lrow[2];
  #pragma unroll
  for(int hi=0;hi<2;++hi){
    mrow[hi] = -1e30f; lrow[hi] = 0.f;
    #pragma unroll
    for(int an=0;an<4;++an) acc_o[hi][an] = zero4;
  }

  const float THR = 11.54f;

  for(int kb=0; kb<Ss/64; ++kb){
    if(kb) __syncthreads();
    #pragma unroll
    for(int ch=0; ch<2; ++ch){
      *(bf16x8*)&Ks[(tid + ch*256)*8] = kreg[ch];
      int vr = r0 + ch*32;
      #pragma unroll
      for(int i=0;i<8;++i){
        int g = i ^ c0;
        VTs[(c0*8 + i)*64 + (vr ^ (g<<3))] = vreg[ch][i];
      }
    }
    if(kb+1 < Ss/64){
      #pragma unroll
      for(int ch=0; ch<2; ++ch){
        int rr = (kb+1)*64 + r0 + ch*32;
        kreg[ch] = *(const bf16x8*)(base + Dd   + (size_t)rr*3072 + khcol);
        vreg[ch] = *(const bf16x8*)(base + 2*Dd + (size_t)rr*3072 + c0*8);
      }
    }
    __syncthreads();

    bf16x8 kf[4][2];
    #pragma unroll
    for(int an=0;an<4;++an){
      int R = an*16 + l15;
      kf[an][0] = *(const bf16x8*)&Ks[R*64 + ((l4     ^ (R&7)))*8];
      kf[an][1] = *(const bf16x8*)&Ks[R*64 + (((4|l4) ^ (R&7)))*8];
    }
    f32x4 sacc[2][4];
    #pragma unroll
    for(int hi=0;hi<2;++hi)
      #pragma unroll
      for(int an=0;an<4;++an) sacc[hi][an] = zero4;
    __builtin_amdgcn_s_setprio(1);
    #pragma unroll
    for(int an=0;an<4;++an){
      sacc[0][an] = mfma16(kf[an][0], aq[0][0], sacc[0][an]);
      sacc[1][an] = mfma16(kf[an][0], aq[1][0], sacc[1][an]);
    }
    #pragma unroll
    for(int an=0;an<4;++an){
      sacc[0][an] = mfma16(kf[an][1], aq[0][1], sacc[0][an]);
      sacc[1][an] = mfma16(kf[an][1], aq[1][1], sacc[1][an]);
    }
    __builtin_amdgcn_s_setprio(0);

    #pragma unroll
    for(int hi=0; hi<2; ++hi){
      float mx = -1e30f;
      #pragma unroll
      for(int an=0;an<4;++an)
        #pragma unroll
        for(int j=0;j<4;++j) mx = fmaxf(mx, sacc[hi][an][j]);
      mx = fmaxf(mx, __shfl_xor(mx, 16));
      mx = fmaxf(mx, __shfl_xor(mx, 32));
      bool grow = mx > mrow[hi] + THR;
      if(__any(grow)){
        float mnew = fmaxf(mrow[hi], mx);
        float corr = exp2f(mrow[hi] - mnew);
        mrow[hi] = mnew;
        lrow[hi] *= corr;
        float cj[4];
        #pragma unroll
        for(int j=0;j<4;++j) cj[j] = __shfl(corr, l4*4 + j);
        #pragma unroll
        for(int an=0;an<4;++an)
          #pragma unroll
          for(int j=0;j<4;++j) acc_o[hi][an][j] *= cj[j];
      }
      float psum = 0.f;
      #pragma unroll
      for(int an=0;an<4;++an)
        #pragma unroll
        for(int j=0;j<4;++j){
          float pv = exp2f(sacc[hi][an][j] - mrow[hi]);
          sacc[hi][an][j] = pv; psum += pv;
        }
      psum += __shfl_xor(psum, 16);
      psum += __shfl_xor(psum, 32);
      lrow[hi] += psum;

      int prow = w*32 + hi*16 + l15;
      int pg = (l15 & 7) << 3;
      #pragma unroll
      for(int an=0;an<4;++an)
        #pragma unroll
        for(int j=0;j<4;++j)
          Ps[prow*64 + ((an*16 + l4*4 + j) ^ pg)] = f2bfs(sacc[hi][an][j]);
    }

    int pgme = (l15 & 7) << 3;
    bf16x8 pa[2][2];
    #pragma unroll
    for(int hi=0;hi<2;++hi){
      int prow = w*32 + hi*16 + l15;
      pa[hi][0] = *(const bf16x8*)&Ps[prow*64 + ((l4*8)      ^ pgme)];
      pa[hi][1] = *(const bf16x8*)&Ps[prow*64 + ((32 + l4*8) ^ pgme)];
    }
    bf16x8 vf[4][2];
    #pragma unroll
    for(int an2=0;an2<4;++an2){
      int dR = an2*16 + l15;
      int g = ((dR & 7) ^ ((dR >> 3) & 7)) << 3;
      vf[an2][0] = *(const bf16x8*)&VTs[dR*64 + ((l4*8)      ^ g)];
      vf[an2][1] = *(const bf16x8*)&VTs[dR*64 + ((32 + l4*8) ^ g)];
    }
    __builtin_amdgcn_s_setprio(1);
    #pragma unroll
    for(int an2=0;an2<4;++an2){
      acc_o[0][an2] = mfma16(pa[0][0], vf[an2][0], acc_o[0][an2]);
      acc_o[1][an2] = mfma16(pa[1][0], vf[an2][0], acc_o[1][an2]);
    }
    #pragma unroll
    for(int an2=0;an2<4;++an2){
      acc_o[0][an2] = mfma16(pa[0][1], vf[an2][1], acc_o[0][an2]);
      acc_o[1][an2] = mfma16(pa[1][1], vf[an2][1], acc_o[1][an2]);
    }
    __builtin_amdgcn_s_setprio(0);
  }

  #pragma unroll
  for(int hi=0;hi<2;++hi){
    float lr[4];
    #pragma unroll
    for(int j=0;j<4;++j) lr[j] = __shfl(lrow[hi], l4*4 + j);
    #pragma unroll
    for(int an2=0;an2<4;++an2)
      #pragma unroll
      for(int j=0;j<4;++j){
        int r = qb*128 + w*32 + hi*16 + l4*4 + j;
        float ov = acc_o[hi][an2][j] / lr[j];
        obuf[((size_t)b*Ss + r)*Dd + h*HD + an2*16 + l15] = f2bf(ov);
      }
  }
}

} // namespace

extern "C" void kernel_launch(void* const* d_in, const int* in_sizes, int n_in,
                              void* d_out, int out_size, void* d_ws, size_t ws_size,
                              hipStream_t stream){
  const float* x      = (const float*)d_in[0];
  const float* c      = (const float*)d_in[1];
  const float* w_qkv  = (const float*)d_in[2];
  const float* b_qkv  = (const float*)d_in[3];
  const float* w_proj = (const float*)d_in[4];
  const float* b_proj = (const float*)d_in[5];
  const float* w12    = (const float*)d_in[6];
  const float* b12    = (const float*)d_in[7];
  const float* w3     = (const float*)d_in[8];
  const float* b3     = (const float*)d_in[9];
  const float* w_ada  = (const float*)d_in[10];
  const float* b_ada  = (const float*)d_in[11];
  const float* n1w    = (const float*)d_in[12];
  const float* n2w    = (const float*)d_in[13];
  const float* qnw    = (const float*)d_in[14];
  const float* knw    = (const float*)d_in[15];
  float* out = (float*)d_out;
  (void)in_sizes; (void)n_in; (void)out_size;

  constexpr size_t WS_NEED = 227254272ull;
  if (ws_size < WS_NEED) return;

  char* ws = (char*)d_ws;
  float*  silu_c = (float*)(ws + 0);
  float*  ada    = (float*)(ws + 65536);
  float2* ropet  = (float2*)(ws + 458752);
  bf16*   wqkvT  = (bf16*)(ws + 720896);
  bf16*   wprojT = (bf16*)(ws + 7012352);
  bf16*   w12T   = (bf16*)(ws + 9109504);
  bf16*   w3T    = (bf16*)(ws + 20291584);
  bf16*   hbuf   = (bf16*)(ws + 25927680);
  bf16*   qkvb   = (bf16*)(ws + 59482112);
  float*  xmid   = (float*)(ws + 160145408);
  bf16*   obuf   = hbuf;
  bf16*   h2     = hbuf;
  bf16*   mlpmid = qkvb;

  k_silu<<<64,256,0,stream>>>(c, silu_c, Bb*Dd);
  k_rope_tab<<<128,256,0,stream>>>(ropet);
  k_ada<<<96,256,0,stream>>>(silu_c, w_ada, b_ada, ada);
  k_transpose<<<dim3(32,96),256,0,stream>>>(w_qkv, wqkvT, 1024, 3072, 1024);
  k_transpose<<<dim3(32,32),256,0,stream>>>(w_proj, wprojT, 1024, 1024, 1024);
  k_transpose<<<dim3(32,171),256,0,stream>>>(w12, w12T, 1024, 5460, 1024);
  k_transpose<<<dim3(86,32),256,0,stream>>>(w3, w3T, 2730, 1024, 2752);

  // attention branch
  k_norm_mod<<<NR,256,0,stream>>>(x, n1w, ada + 0, ada + 1024, hbuf);
  k_gemm8<0><<<dim3(64,12),512,0,stream>>>(hbuf,1024, wqkvT,1024,
      b_qkv, 1024, nullptr,nullptr, qkvb,3072);
  k_qknorm<<<NR,256,0,stream>>>(qkvb, qnw, knw, ropet);
  k_attn<<<2048,256,0,stream>>>(qkvb, obuf);
  k_gemm8<1><<<dim3(64,4),512,0,stream>>>(obuf,1024, wprojT,1024,
      b_proj, 1024, x, ada + 2048, xmid,1024);

  // MLP branch
  k_norm_mod<<<NR,256,0,stream>>>(xmid, n2w, ada + 3072, ada + 4096, h2);
  k_gemm3<<<dim3(128,43),256,0,stream>>>(h2,1024, w12T,(long long)MLPH*1024,1024,
      b12, b12 + MLPH, 1024, mlpmid, MLPH_PAD);
  k_gemm8<1><<<dim3(64,4),512,0,stream>>>(mlpmid,MLPH_PAD, w3T,MLPH_PAD,
      b3, MLPH_PAD, xmid, ada + 5120, out,1024);
}